// Round 1
// baseline (795.655 us; speedup 1.0000x reference)
//
#include <hip/hip_runtime.h>
#include <hip/hip_bf16.h>

#define NB 16
#define LC 2048
#define LQ 256
#define DD 256
#define NEGINF -1e30f

// ---------- block reduction helpers (256 threads = 4 waves of 64) ----------
__device__ __forceinline__ float block_reduce_sum_256(float v, float* buf) {
    #pragma unroll
    for (int o = 32; o > 0; o >>= 1) v += __shfl_xor(v, o, 64);
    int w = threadIdx.x >> 6;
    __syncthreads();
    if ((threadIdx.x & 63) == 0) buf[w] = v;
    __syncthreads();
    return buf[0] + buf[1] + buf[2] + buf[3];
}

__device__ __forceinline__ float block_reduce_max_256(float v, float* buf) {
    #pragma unroll
    for (int o = 32; o > 0; o >>= 1) v = fmaxf(v, __shfl_xor(v, o, 64));
    int w = threadIdx.x >> 6;
    __syncthreads();
    if ((threadIdx.x & 63) == 0) buf[w] = v;
    __syncthreads();
    return fmaxf(fmaxf(buf[0], buf[1]), fmaxf(buf[2], buf[3]));
}

// ---------- k0: s0c[b,i] = dot(c[b,i,:], c_weight); s1q[b,j] = dot(q[b,j,:], q_weight)+bias
__global__ __launch_bounds__(256) void k0_rowdots(
        const float* __restrict__ c, const float* __restrict__ q,
        const float* __restrict__ c_w, const float* __restrict__ q_w,
        const float* __restrict__ bias,
        float* __restrict__ s0c, float* __restrict__ s1q) {
    __shared__ float buf[4];
    int bid = blockIdx.x;
    int t = threadIdx.x;
    const int nC = NB * LC;
    float v;
    if (bid < nC) {
        v = c[(size_t)bid * DD + t] * c_w[t];
    } else {
        int r = bid - nC;
        v = q[(size_t)r * DD + t] * q_w[t];
    }
    float s = block_reduce_sum_256(v, buf);
    if (t == 0) {
        if (bid < nC) s0c[bid] = s;
        else          s1q[bid - nC] = s + bias[0];
    }
}

// ---------- k1: S tile [16 x 256] = (c*cqw) @ q^T + s0 + s1; also per-chunk column stats
#define K1_TM 16
#define K1_KT 32
#define QT_PAD 260
__global__ __launch_bounds__(256) void k1_S(
        const float* __restrict__ c, const float* __restrict__ q,
        const float* __restrict__ cqw, const float* __restrict__ cmask,
        const float* __restrict__ s0c, const float* __restrict__ s1q,
        float* __restrict__ S, float* __restrict__ pm, float* __restrict__ ps) {
    __shared__ float cwA[K1_TM][K1_KT];
    __shared__ float qT[K1_KT][QT_PAD];
    int b  = blockIdx.y;
    int i0 = blockIdx.x * K1_TM;
    int t  = threadIdx.x;
    const float* cb = c + (size_t)b * LC * DD;
    const float* qb = q + (size_t)b * LQ * DD;

    float acc[K1_TM];
    #pragma unroll
    for (int r = 0; r < K1_TM; r++) acc[r] = 0.f;

    for (int k0 = 0; k0 < DD; k0 += K1_KT) {
        __syncthreads();
        // A tile: cwA[r][kk] = c[i0+r][k0+kk] * cqw[k0+kk]   (512 elems)
        #pragma unroll
        for (int l = 0; l < 2; l++) {
            int e = t + l * 256;
            int r = e >> 5, kk = e & 31;
            cwA[r][kk] = cb[(size_t)(i0 + r) * DD + k0 + kk] * cqw[k0 + kk];
        }
        // B tile: qT[kk][j] = q[j][k0+kk]; thread t owns row j=t, 8 float4 along k
        const float4* qrow = (const float4*)(qb + (size_t)t * DD + k0);
        #pragma unroll
        for (int l = 0; l < 8; l++) {
            float4 v = qrow[l];
            qT[l * 4 + 0][t] = v.x;
            qT[l * 4 + 1][t] = v.y;
            qT[l * 4 + 2][t] = v.z;
            qT[l * 4 + 3][t] = v.w;
        }
        __syncthreads();
        #pragma unroll
        for (int kk = 0; kk < K1_KT; kk++) {
            float qv = qT[kk][t];
            #pragma unroll
            for (int r = 0; r < K1_TM; r++) acc[r] += cwA[r][kk] * qv;
        }
    }

    float s1 = s1q[b * LQ + t];
    // store S and accumulate column-softmax partial stats (masked by c_mask over i)
    float m = NEGINF;
    float sv_arr[K1_TM];
    #pragma unroll
    for (int r = 0; r < K1_TM; r++) {
        float sv = acc[r] + s0c[b * LC + i0 + r] + s1;
        sv_arr[r] = sv;
        S[((size_t)b * LC + i0 + r) * LQ + t] = sv;
        float cm = cmask[b * LC + i0 + r];
        float x2 = sv * cm + (1.f - cm) * NEGINF;
        m = fmaxf(m, x2);
    }
    float ssum = 0.f;
    #pragma unroll
    for (int r = 0; r < K1_TM; r++) {
        float cm = cmask[b * LC + i0 + r];
        float x2 = sv_arr[r] * cm + (1.f - cm) * NEGINF;
        ssum += __expf(x2 - m);
    }
    int chunk = blockIdx.x;  // 128 chunks per batch
    pm[((size_t)b * (LC / K1_TM) + chunk) * LQ + t] = m;
    ps[((size_t)b * (LC / K1_TM) + chunk) * LQ + t] = ssum;
}

// ---------- k2b: combine 128 per-chunk partials -> colM, colInv (per b, j)
__global__ __launch_bounds__(256) void k2b_colstats(
        const float* __restrict__ pm, const float* __restrict__ ps,
        float* __restrict__ colM, float* __restrict__ colInv) {
    int b = blockIdx.x, t = threadIdx.x;
    float m = NEGINF, s = 0.f;
    const int NCH = LC / K1_TM;
    for (int ch = 0; ch < NCH; ch++) {
        float pmv = pm[((size_t)b * NCH + ch) * LQ + t];
        float psv = ps[((size_t)b * NCH + ch) * LQ + t];
        float mn = fmaxf(m, pmv);
        s = s * __expf(m - mn) + psv * __expf(pmv - mn);
        m = mn;
    }
    colM[b * LQ + t] = m;
    colInv[b * LQ + t] = 1.f / s;
}

// ---------- k3: A2C[b,j,d] = sum_i P2[i,j] * c[b,i,d]
#define K3_TJ 16
#define K3_KT 32
__global__ __launch_bounds__(256) void k3_A2C(
        const float* __restrict__ S, const float* __restrict__ c,
        const float* __restrict__ cmask,
        const float* __restrict__ colM, const float* __restrict__ colInv,
        float* __restrict__ A2C) {
    __shared__ float P[K3_TJ][K3_KT + 1];  // [j][i]
    int b  = blockIdx.y;
    int j0 = blockIdx.x * K3_TJ;
    int t  = threadIdx.x;
    float acc[K3_TJ];
    #pragma unroll
    for (int r = 0; r < K3_TJ; r++) acc[r] = 0.f;

    for (int i0 = 0; i0 < LC; i0 += K3_KT) {
        __syncthreads();
        #pragma unroll
        for (int l = 0; l < 2; l++) {
            int e = t + l * 256;   // 512 elems
            int kk = e >> 4, r = e & 15;
            float sv = S[((size_t)b * LC + i0 + kk) * LQ + j0 + r];
            float cm = cmask[b * LC + i0 + kk];
            float x2 = sv * cm + (1.f - cm) * NEGINF;
            P[r][kk] = __expf(x2 - colM[b * LQ + j0 + r]) * colInv[b * LQ + j0 + r];
        }
        __syncthreads();
        #pragma unroll
        for (int kk = 0; kk < K3_KT; kk++) {
            float cv = c[((size_t)b * LC + i0 + kk) * DD + t];
            #pragma unroll
            for (int r = 0; r < K3_TJ; r++) acc[r] += P[r][kk] * cv;
        }
    }
    #pragma unroll
    for (int r = 0; r < K3_TJ; r++)
        A2C[((size_t)b * LQ + j0 + r) * DD + t] = acc[r];
}

// ---------- k4: row softmax of S (q_mask) + C2Q = S1@q + Q2C = S1@A2C + fused output
__global__ __launch_bounds__(256) void k4_out(
        const float* __restrict__ S, const float* __restrict__ q,
        const float* __restrict__ A2C, const float* __restrict__ c,
        const float* __restrict__ qmask, float* __restrict__ out) {
    __shared__ float P1[16][LQ];   // 16 KB
    __shared__ float buf[4];
    int b  = blockIdx.y;
    int i0 = blockIdx.x * 16;
    int t  = threadIdx.x;

    float qm = qmask[b * LQ + t];
    float maskadd = (1.f - qm) * NEGINF;
    #pragma unroll
    for (int r = 0; r < 16; r++) {
        float sv = S[((size_t)b * LC + i0 + r) * LQ + t];
        P1[r][t] = sv * qm + maskadd;
    }
    __syncthreads();
    for (int r = 0; r < 16; r++) {
        float v = P1[r][t];
        float m = block_reduce_max_256(v, buf);
        float p = __expf(v - m);
        float Z = block_reduce_sum_256(p, buf);
        P1[r][t] = p * (1.f / Z);
    }
    __syncthreads();

    float acc1[16], acc2[16];
    #pragma unroll
    for (int r = 0; r < 16; r++) { acc1[r] = 0.f; acc2[r] = 0.f; }
    const float* qb = q   + (size_t)b * LQ * DD;
    const float* ab = A2C + (size_t)b * LQ * DD;
    for (int k = 0; k < LQ; k++) {
        float qv = qb[(size_t)k * DD + t];
        float av = ab[(size_t)k * DD + t];
        #pragma unroll
        for (int r = 0; r < 16; r++) {
            float p = P1[r][k];
            acc1[r] += p * qv;
            acc2[r] += p * av;
        }
    }
    #pragma unroll
    for (int r = 0; r < 16; r++) {
        float cv = c[((size_t)b * LC + i0 + r) * DD + t];
        size_t ob = ((size_t)b * LC + i0 + r) * (4 * DD);
        out[ob + 0 * DD + t] = cv;
        out[ob + 1 * DD + t] = acc1[r];
        out[ob + 2 * DD + t] = cv * acc1[r];
        out[ob + 3 * DD + t] = cv * acc2[r];
    }
}

extern "C" void kernel_launch(void* const* d_in, const int* in_sizes, int n_in,
                              void* d_out, int out_size, void* d_ws, size_t ws_size,
                              hipStream_t stream) {
    const float* c     = (const float*)d_in[0];
    const float* q     = (const float*)d_in[1];
    const float* cmask = (const float*)d_in[2];
    const float* qmask = (const float*)d_in[3];
    const float* cqw   = (const float*)d_in[4];
    const float* c_w   = (const float*)d_in[5];
    const float* q_w   = (const float*)d_in[6];
    const float* bias  = (const float*)d_in[7];
    float* out = (float*)d_out;

    // workspace layout (floats)
    float* ws     = (float*)d_ws;
    float* S      = ws;                       // 16*2048*256  = 8,388,608
    float* s0c    = S      + (size_t)NB * LC * LQ;      // 32,768
    float* s1q    = s0c    + (size_t)NB * LC;           // 4,096
    float* pm     = s1q    + (size_t)NB * LQ;           // 16*128*256 = 524,288
    float* ps     = pm     + (size_t)NB * (LC / K1_TM) * LQ;
    float* colM   = ps     + (size_t)NB * (LC / K1_TM) * LQ;  // 4,096
    float* colInv = colM   + (size_t)NB * LQ;                 // 4,096
    float* A2C    = colInv + (size_t)NB * LQ;                 // 1,048,576

    k0_rowdots<<<dim3(NB * LC + NB * LQ), dim3(256), 0, stream>>>(
        c, q, c_w, q_w, bias, s0c, s1q);
    k1_S<<<dim3(LC / K1_TM, NB), dim3(256), 0, stream>>>(
        c, q, cqw, cmask, s0c, s1q, S, pm, ps);
    k2b_colstats<<<dim3(NB), dim3(256), 0, stream>>>(pm, ps, colM, colInv);
    k3_A2C<<<dim3(LQ / K3_TJ, NB), dim3(256), 0, stream>>>(
        S, c, cmask, colM, colInv, A2C);
    k4_out<<<dim3(LC / 16, NB), dim3(256), 0, stream>>>(
        S, q, A2C, c, qmask, out);
}

// Round 2
// 434.729 us; speedup vs baseline: 1.8302x; 1.8302x over previous
//
#include <hip/hip_runtime.h>
#include <hip/hip_bf16.h>

#define NB 16
#define LC 2048
#define LQ 256
#define DD 256
#define NEGINF -1e30f

typedef __attribute__((ext_vector_type(8))) short bf16x8;
typedef __attribute__((ext_vector_type(4))) float f32x4;

#define MFMA16(a, b, c) __builtin_amdgcn_mfma_f32_16x16x32_bf16((a), (b), (c), 0, 0, 0)

typedef const unsigned int __attribute__((address_space(1))) glb_u32;
typedef unsigned int __attribute__((address_space(3))) lds_u32;

__device__ __forceinline__ void gload_lds16(const void* g, void* l) {
    __builtin_amdgcn_global_load_lds((glb_u32*)g, (lds_u32*)l, 16, 0, 0);
}

__device__ __forceinline__ short f2b(float x) {
    unsigned u = __float_as_uint(x);
    unsigned r = (u + 0x7fffu + ((u >> 16) & 1u)) >> 16;
    return (short)r;
}
__device__ __forceinline__ float b2f(short s) {
    return __uint_as_float(((unsigned)(unsigned short)s) << 16);
}

// ---------- k0: wave-per-row dots: s0c[b,i]=c.c_w ; s1q[b,j]=q.q_w+bias ----------
__global__ __launch_bounds__(256) void k0_rowdots(
        const float* __restrict__ c, const float* __restrict__ q,
        const float* __restrict__ c_w, const float* __restrict__ q_w,
        const float* __restrict__ bias,
        float* __restrict__ s0c, float* __restrict__ s1q) {
    int R = blockIdx.x * 4 + (threadIdx.x >> 6);
    int l = threadIdx.x & 63;
    const int nC = NB * LC;
    float4 v, wv;
    if (R < nC) {
        v  = *(const float4*)(c + (size_t)R * DD + l * 4);
        wv = *(const float4*)(c_w + l * 4);
    } else {
        int r = R - nC;
        v  = *(const float4*)(q + (size_t)r * DD + l * 4);
        wv = *(const float4*)(q_w + l * 4);
    }
    float s = v.x * wv.x + v.y * wv.y + v.z * wv.z + v.w * wv.w;
    #pragma unroll
    for (int o = 32; o > 0; o >>= 1) s += __shfl_xor(s, o, 64);
    if (l == 0) {
        if (R < nC) s0c[R] = s;
        else        s1q[R - nC] = s + bias[0];
    }
}

// ---------- prep_cb: cb16 = bf16(c * cqw), elementwise ----------
__global__ __launch_bounds__(256) void prep_cb(
        const float* __restrict__ c, const float* __restrict__ cqw,
        short* __restrict__ cb16) {
    size_t idx = (size_t)blockIdx.x * 256 + threadIdx.x;   // float4 index
    float4 v = ((const float4*)c)[idx];
    int d = (int)((idx * 4) & 255);
    float4 wv = *(const float4*)(cqw + d);
    ushort4 o;
    o.x = (unsigned short)f2b(v.x * wv.x);
    o.y = (unsigned short)f2b(v.y * wv.y);
    o.z = (unsigned short)f2b(v.z * wv.z);
    o.w = (unsigned short)f2b(v.w * wv.w);
    ((ushort4*)cb16)[idx] = o;
}

// ---------- prep_q: qb16 = bf16(q); qT16[b,d,j] = bf16(q[b,j,d]) ----------
__global__ __launch_bounds__(256) void prep_q(
        const float* __restrict__ q, short* __restrict__ qb16,
        short* __restrict__ qT16) {
    __shared__ short T[64 * 65];
    int b = blockIdx.y, j0 = blockIdx.x * 64, t = threadIdx.x;
    for (int dc = 0; dc < 4; ++dc) {
        int dd = t & 63, rg = t >> 6;
        for (int r = rg; r < 64; r += 4) {
            float v = q[((size_t)b * LQ + j0 + r) * DD + dc * 64 + dd];
            short bv = f2b(v);
            qb16[((size_t)b * LQ + j0 + r) * DD + dc * 64 + dd] = bv;
            T[dd * 65 + r] = bv;
        }
        __syncthreads();
        int jj = t & 63;
        for (int dw = t >> 6; dw < 64; dw += 4)
            qT16[((size_t)b * DD + dc * 64 + dw) * LQ + j0 + jj] = T[dw * 65 + jj];
        __syncthreads();
    }
}

// ---------- k1: S = (c*cqw) @ q^T + s0 + s1 (MFMA), store bf16 S + col partial stats
__global__ __launch_bounds__(256) void k1_S(
        const short* __restrict__ cb16, const short* __restrict__ qb16,
        const float* __restrict__ cmask,
        const float* __restrict__ s0c, const float* __restrict__ s1q,
        short* __restrict__ Sb, float* __restrict__ pm, float* __restrict__ ps) {
    __shared__ short As[128 * 64];
    __shared__ short Bs[128 * 64];
    int b  = blockIdx.z;
    int i0 = blockIdx.x * 128;
    int j0 = blockIdx.y * 128;
    int t = threadIdx.x;
    int l = t & 63, w = t >> 6;
    int wr = w >> 1, wc = w & 1;

    f32x4 acc[4][4];
    #pragma unroll
    for (int m = 0; m < 4; ++m)
        #pragma unroll
        for (int n = 0; n < 4; ++n) acc[m][n] = (f32x4){0.f, 0.f, 0.f, 0.f};

    const short* Ag = cb16 + ((size_t)b * LC + i0) * DD;
    const short* Bg = qb16 + ((size_t)b * LQ + j0) * DD;
    int lrow = l >> 3;          // 0..7 row within 8-row chunk
    int lcol = (l & 7) * 8;     // bf16 elem offset within row slice

    for (int kt = 0; kt < DD; kt += 64) {
        __syncthreads();
        #pragma unroll
        for (int r = 0; r < 4; ++r) {
            int chunk = r * 4 + w;          // 0..15, uniform per wave
            int row = chunk * 8 + lrow;     // 0..127
            gload_lds16(Ag + (size_t)row * DD + kt + lcol, As + chunk * 512);
            gload_lds16(Bg + (size_t)row * DD + kt + lcol, Bs + chunk * 512);
        }
        __syncthreads();
        #pragma unroll
        for (int kf = 0; kf < 2; ++kf) {
            bf16x8 a[4], bb[4];
            #pragma unroll
            for (int m = 0; m < 4; ++m)
                a[m] = *(const bf16x8*)((const char*)As +
                        (wr * 64 + m * 16 + (l & 15)) * 128 + kf * 64 + (l >> 4) * 16);
            #pragma unroll
            for (int n = 0; n < 4; ++n)
                bb[n] = *(const bf16x8*)((const char*)Bs +
                        (wc * 64 + n * 16 + (l & 15)) * 128 + kf * 64 + (l >> 4) * 16);
            #pragma unroll
            for (int m = 0; m < 4; ++m)
                #pragma unroll
                for (int n = 0; n < 4; ++n)
                    acc[m][n] = MFMA16(a[m], bb[n], acc[m][n]);
        }
    }

    // epilogue: add s0c + s1q, round to bf16, store S, fused column partial stats
    int jb = j0 + wc * 64;
    float s1v[4];
    #pragma unroll
    for (int n = 0; n < 4; ++n) s1v[n] = s1q[b * LQ + jb + n * 16 + (l & 15)];
    float s0r[4][4], cmr[4][4];
    #pragma unroll
    for (int m = 0; m < 4; ++m)
        #pragma unroll
        for (int reg = 0; reg < 4; ++reg) {
            int il = wr * 64 + m * 16 + (l >> 4) * 4 + reg;
            s0r[m][reg] = s0c[b * LC + i0 + il];
            cmr[m][reg] = cmask[b * LC + i0 + il];
        }
    #pragma unroll
    for (int m = 0; m < 4; ++m)
        #pragma unroll
        for (int n = 0; n < 4; ++n)
            #pragma unroll
            for (int reg = 0; reg < 4; ++reg) {
                float v = acc[m][n][reg] + s0r[m][reg] + s1v[n];
                short sb = f2b(v);
                int il = wr * 64 + m * 16 + (l >> 4) * 4 + reg;
                Sb[((size_t)b * LC + i0 + il) * LQ + jb + n * 16 + (l & 15)] = sb;
                acc[m][n][reg] = b2f(sb);
            }
    #pragma unroll
    for (int n = 0; n < 4; ++n) {
        float x2v[16];
        float mx = NEGINF;
        #pragma unroll
        for (int m = 0; m < 4; ++m)
            #pragma unroll
            for (int reg = 0; reg < 4; ++reg) {
                float cm = cmr[m][reg];
                float x2 = acc[m][n][reg] * cm + (1.f - cm) * NEGINF;
                x2v[m * 4 + reg] = x2;
                mx = fmaxf(mx, x2);
            }
        float ss = 0.f;
        #pragma unroll
        for (int e = 0; e < 16; ++e) ss += __expf(x2v[e] - mx);
        #pragma unroll
        for (int off = 16; off <= 32; off <<= 1) {
            float om = __shfl_xor(mx, off, 64);
            float os = __shfl_xor(ss, off, 64);
            float nm = fmaxf(mx, om);
            ss = ss * __expf(mx - nm) + os * __expf(om - nm);
            mx = nm;
        }
        if (l < 16) {
            size_t idx = ((size_t)b * 32 + blockIdx.x * 2 + wr) * LQ + jb + n * 16 + l;
            pm[idx] = mx;
            ps[idx] = ss;
        }
    }
}

// ---------- k2b: combine 32 chunk partials -> colM, colInv ----------
__global__ __launch_bounds__(256) void k2b_colstats(
        const float* __restrict__ pm, const float* __restrict__ ps,
        float* __restrict__ colM, float* __restrict__ colInv) {
    int b = blockIdx.x, t = threadIdx.x;
    float m = NEGINF, s = 0.f;
    for (int ch = 0; ch < 32; ++ch) {
        float pmv = pm[((size_t)b * 32 + ch) * LQ + t];
        float psv = ps[((size_t)b * 32 + ch) * LQ + t];
        float mn = fmaxf(m, pmv);
        s = s * __expf(m - mn) + psv * __expf(pmv - mn);
        m = mn;
    }
    colM[b * LQ + t] = m;
    colInv[b * LQ + t] = 1.f / s;
}

// ---------- k3: A2CT[b,d,j] = sum_i P2[i,j] * c[i,d]  (MFMA, transposed staging)
__global__ __launch_bounds__(256) void k3_A2C(
        const short* __restrict__ Sb, const float* __restrict__ c,
        const float* __restrict__ cmask,
        const float* __restrict__ colM, const float* __restrict__ colInv,
        short* __restrict__ A2CT) {
    __shared__ short At[32 * 72];    // [j][i], pad to 72
    __shared__ short Bt[128 * 72];   // [d][i], pad to 72
    __shared__ float Ot[128 * 33];
    int b  = blockIdx.z;
    int j0 = blockIdx.x * 32;
    int d0 = blockIdx.y * 128;
    int t = threadIdx.x, l = t & 63, w = t >> 6;

    float cM = colM[b * LQ + j0 + (t & 31)];
    float cI = colInv[b * LQ + j0 + (t & 31)];

    f32x4 acc[2][2];
    #pragma unroll
    for (int m = 0; m < 2; ++m)
        #pragma unroll
        for (int n = 0; n < 2; ++n) acc[m][n] = (f32x4){0.f, 0.f, 0.f, 0.f};

    for (int k0 = 0; k0 < LC; k0 += 64) {
        __syncthreads();
        // stage At: P2 tile [32 j][64 i] (transpose of S with exp applied)
        int jj = t & 31;
        #pragma unroll
        for (int ii = 0; ii < 8; ++ii) {
            int il = (t >> 5) + 8 * ii;
            float sv = b2f(Sb[((size_t)b * LC + k0 + il) * LQ + j0 + jj]);
            float cm = cmask[b * LC + k0 + il];
            float x2 = sv * cm + (1.f - cm) * NEGINF;
            At[jj * 72 + il] = f2b(__expf(x2 - cM) * cI);
        }
        // stage Bt: c^T tile [128 d][64 i]
        int dl = t & 127;
        #pragma unroll
        for (int ii = 0; ii < 32; ++ii) {
            int il = (t >> 7) + 2 * ii;
            float v = c[((size_t)b * LC + k0 + il) * DD + d0 + dl];
            Bt[dl * 72 + il] = f2b(v);
        }
        __syncthreads();
        #pragma unroll
        for (int kf = 0; kf < 2; ++kf) {
            bf16x8 a[2], bb[2];
            #pragma unroll
            for (int m = 0; m < 2; ++m)
                a[m] = *(const bf16x8*)((const char*)At +
                        (m * 16 + (l & 15)) * 144 + kf * 64 + (l >> 4) * 16);
            #pragma unroll
            for (int n = 0; n < 2; ++n)
                bb[n] = *(const bf16x8*)((const char*)Bt +
                        (w * 32 + n * 16 + (l & 15)) * 144 + kf * 64 + (l >> 4) * 16);
            #pragma unroll
            for (int m = 0; m < 2; ++m)
                #pragma unroll
                for (int n = 0; n < 2; ++n)
                    acc[m][n] = MFMA16(a[m], bb[n], acc[m][n]);
        }
    }
    __syncthreads();
    #pragma unroll
    for (int m = 0; m < 2; ++m)
        #pragma unroll
        for (int n = 0; n < 2; ++n)
            #pragma unroll
            for (int reg = 0; reg < 4; ++reg)
                Ot[(w * 32 + n * 16 + (l & 15)) * 33 + m * 16 + (l >> 4) * 4 + reg] =
                    acc[m][n][reg];
    __syncthreads();
    int jj2 = t & 31;
    #pragma unroll
    for (int r = 0; r < 16; ++r) {
        int dl2 = (t >> 5) + 8 * r;
        A2CT[((size_t)b * DD + d0 + dl2) * LQ + j0 + jj2] = f2b(Ot[dl2 * 33 + jj2]);
    }
}

// ---------- k4: row softmax (q_mask) + C2Q=S1@q + Q2C=S1@A2C + fused epilogue
__global__ __launch_bounds__(256) void k4_out(
        const short* __restrict__ Sb, const short* __restrict__ qT16,
        const short* __restrict__ A2CT, const float* __restrict__ c,
        const float* __restrict__ qmask, float* __restrict__ out) {
    __shared__ short P1[64 * 256];   // XOR-swizzled rows
    int b = blockIdx.y, i0 = blockIdx.x * 64;
    int t = threadIdx.x, l = t & 63, w = t >> 6;

    float4 qm4 = *(const float4*)(qmask + b * LQ + l * 4);
    for (int rr = 0; rr < 16; ++rr) {
        int r = rr * 4 + w;
        short4 s4 = *(const short4*)(Sb + ((size_t)b * LC + i0 + r) * LQ + l * 4);
        float x0 = b2f(s4.x) * qm4.x + (1.f - qm4.x) * NEGINF;
        float x1 = b2f(s4.y) * qm4.y + (1.f - qm4.y) * NEGINF;
        float x2 = b2f(s4.z) * qm4.z + (1.f - qm4.z) * NEGINF;
        float x3 = b2f(s4.w) * qm4.w + (1.f - qm4.w) * NEGINF;
        float mx = fmaxf(fmaxf(x0, x1), fmaxf(x2, x3));
        #pragma unroll
        for (int o = 32; o > 0; o >>= 1) mx = fmaxf(mx, __shfl_xor(mx, o, 64));
        float p0 = __expf(x0 - mx), p1 = __expf(x1 - mx);
        float p2 = __expf(x2 - mx), p3 = __expf(x3 - mx);
        float Z = p0 + p1 + p2 + p3;
        #pragma unroll
        for (int o = 32; o > 0; o >>= 1) Z += __shfl_xor(Z, o, 64);
        float inv = 1.f / Z;
        ushort4 pk;
        pk.x = (unsigned short)f2b(p0 * inv);
        pk.y = (unsigned short)f2b(p1 * inv);
        pk.z = (unsigned short)f2b(p2 * inv);
        pk.w = (unsigned short)f2b(p3 * inv);
        int byte = r * 512 + l * 8;
        *(ushort4*)((char*)P1 + (byte ^ ((r & 7) << 4))) = pk;
    }
    __syncthreads();

    f32x4 acc1[4][4], acc2[4][4];
    #pragma unroll
    for (int m = 0; m < 4; ++m)
        #pragma unroll
        for (int n = 0; n < 4; ++n) {
            acc1[m][n] = (f32x4){0.f, 0.f, 0.f, 0.f};
            acc2[m][n] = (f32x4){0.f, 0.f, 0.f, 0.f};
        }
    const short* qTb = qT16 + (size_t)b * DD * LQ;
    const short* aTb = A2CT + (size_t)b * DD * LQ;
    int d0w = w * 64;
    for (int kf = 0; kf < 8; ++kf) {
        bf16x8 a[4];
        #pragma unroll
        for (int m = 0; m < 4; ++m) {
            int row = m * 16 + (l & 15);
            int byte = row * 512 + kf * 64 + (l >> 4) * 16;
            a[m] = *(const bf16x8*)((const char*)P1 + (byte ^ ((row & 7) << 4)));
        }
        #pragma unroll
        for (int n = 0; n < 4; ++n) {
            int d = d0w + n * 16 + (l & 15);
            size_t off = (size_t)d * LQ + kf * 32 + (l >> 4) * 8;
            bf16x8 bq = *(const bf16x8*)(qTb + off);
            bf16x8 ba = *(const bf16x8*)(aTb + off);
            #pragma unroll
            for (int m = 0; m < 4; ++m) {
                acc1[m][n] = MFMA16(a[m], bq, acc1[m][n]);
                acc2[m][n] = MFMA16(a[m], ba, acc2[m][n]);
            }
        }
    }
    #pragma unroll
    for (int m = 0; m < 4; ++m)
        #pragma unroll
        for (int n = 0; n < 4; ++n)
            #pragma unroll
            for (int reg = 0; reg < 4; ++reg) {
                int i = i0 + m * 16 + (l >> 4) * 4 + reg;
                int d = d0w + n * 16 + (l & 15);
                float cv = c[((size_t)b * LC + i) * DD + d];
                size_t ob = ((size_t)b * LC + i) * (size_t)(4 * DD);
                float v1 = acc1[m][n][reg], v2 = acc2[m][n][reg];
                out[ob + d]           = cv;
                out[ob + 256 + d]     = v1;
                out[ob + 512 + d]     = cv * v1;
                out[ob + 768 + d]     = cv * v2;
            }
}

extern "C" void kernel_launch(void* const* d_in, const int* in_sizes, int n_in,
                              void* d_out, int out_size, void* d_ws, size_t ws_size,
                              hipStream_t stream) {
    const float* c     = (const float*)d_in[0];
    const float* q     = (const float*)d_in[1];
    const float* cmask = (const float*)d_in[2];
    const float* qmask = (const float*)d_in[3];
    const float* cqw   = (const float*)d_in[4];
    const float* c_w   = (const float*)d_in[5];
    const float* q_w   = (const float*)d_in[6];
    const float* bias  = (const float*)d_in[7];
    float* out = (float*)d_out;

    char* w = (char*)d_ws;
    short* Sb    = (short*)(w);                  // 16,777,216 B
    short* cb16  = (short*)(w + 16777216);       // 16,777,216 B
    short* qb16  = (short*)(w + 33554432);       //  2,097,152 B
    short* qT16  = (short*)(w + 35651584);       //  2,097,152 B
    short* A2CT  = (short*)(w + 37748736);       //  2,097,152 B
    float* s0c   = (float*)(w + 39845888);       //    131,072 B
    float* s1q   = (float*)(w + 39976960);       //     16,384 B
    float* pm    = (float*)(w + 39993344);       //    524,288 B
    float* ps    = (float*)(w + 40517632);       //    524,288 B
    float* colM  = (float*)(w + 41041920);       //     16,384 B
    float* colInv= (float*)(w + 41058304);       //     16,384 B  (end 41,074,688)

    k0_rowdots<<<dim3((NB * LC + NB * LQ) / 4), dim3(256), 0, stream>>>(
        c, q, c_w, q_w, bias, s0c, s1q);
    prep_cb<<<dim3(NB * LC * DD / 1024), dim3(256), 0, stream>>>(c, cqw, cb16);
    prep_q<<<dim3(LQ / 64, NB), dim3(256), 0, stream>>>(q, qb16, qT16);
    k1_S<<<dim3(LC / 128, LQ / 128, NB), dim3(256), 0, stream>>>(
        cb16, qb16, cmask, s0c, s1q, Sb, pm, ps);
    k2b_colstats<<<dim3(NB), dim3(256), 0, stream>>>(pm, ps, colM, colInv);
    k3_A2C<<<dim3(LQ / 32, DD / 128, NB), dim3(256), 0, stream>>>(
        Sb, c, cmask, colM, colInv, A2CT);
    k4_out<<<dim3(LC / 64, NB), dim3(256), 0, stream>>>(
        Sb, qT16, A2CT, c, qmask, out);
}

// Round 3
// 178.101 us; speedup vs baseline: 4.4674x; 2.4409x over previous
//
#include <hip/hip_runtime.h>
#include <hip/hip_bf16.h>

#define NB 16
#define LC 2048
#define LQ 256
#define DD 256
#define NEGINF -1e30f

typedef __attribute__((ext_vector_type(8))) short bf16x8;
typedef __attribute__((ext_vector_type(4))) float f32x4;

#define MFMA16(a, b, c) __builtin_amdgcn_mfma_f32_16x16x32_bf16((a), (b), (c), 0, 0, 0)

typedef const unsigned int __attribute__((address_space(1))) glb_u32;
typedef unsigned int __attribute__((address_space(3))) lds_u32;

__device__ __forceinline__ void gload_lds16(const void* g, void* l) {
    __builtin_amdgcn_global_load_lds((glb_u32*)g, (lds_u32*)l, 16, 0, 0);
}

__device__ __forceinline__ short f2b(float x) {
    unsigned u = __float_as_uint(x);
    unsigned r = (u + 0x7fffu + ((u >> 16) & 1u)) >> 16;
    return (short)r;
}
__device__ __forceinline__ float b2f(short s) {
    return __uint_as_float(((unsigned)(unsigned short)s) << 16);
}

// ---------- k0: wave-per-row dots: s0c[b,i]=c.c_w ; s1q[b,j]=q.q_w+bias ----------
__global__ __launch_bounds__(256) void k0_rowdots(
        const float* __restrict__ c, const float* __restrict__ q,
        const float* __restrict__ c_w, const float* __restrict__ q_w,
        const float* __restrict__ bias,
        float* __restrict__ s0c, float* __restrict__ s1q) {
    int R = blockIdx.x * 4 + (threadIdx.x >> 6);
    int l = threadIdx.x & 63;
    const int nC = NB * LC;
    float4 v, wv;
    if (R < nC) {
        v  = *(const float4*)(c + (size_t)R * DD + l * 4);
        wv = *(const float4*)(c_w + l * 4);
    } else {
        int r = R - nC;
        v  = *(const float4*)(q + (size_t)r * DD + l * 4);
        wv = *(const float4*)(q_w + l * 4);
    }
    float s = v.x * wv.x + v.y * wv.y + v.z * wv.z + v.w * wv.w;
    #pragma unroll
    for (int o = 32; o > 0; o >>= 1) s += __shfl_xor(s, o, 64);
    if (l == 0) {
        if (R < nC) s0c[R] = s;
        else        s1q[R - nC] = s + bias[0];
    }
}

// ---------- prep_c16: c16 = bf16(c), elementwise ----------
__global__ __launch_bounds__(256) void prep_c16(
        const float* __restrict__ c, short* __restrict__ c16) {
    size_t idx = (size_t)blockIdx.x * 256 + threadIdx.x;   // float4 index
    float4 v = ((const float4*)c)[idx];
    ushort4 o;
    o.x = (unsigned short)f2b(v.x);
    o.y = (unsigned short)f2b(v.y);
    o.z = (unsigned short)f2b(v.z);
    o.w = (unsigned short)f2b(v.w);
    ((ushort4*)c16)[idx] = o;
}

// ---------- prep_q: qw16 = bf16(q*cqw) row-major; qT16[b,d,j] = bf16(q[b,j,d]) ----
__global__ __launch_bounds__(256) void prep_q(
        const float* __restrict__ q, const float* __restrict__ cqw,
        short* __restrict__ qw16, short* __restrict__ qT16) {
    __shared__ float T[64][65];
    int b = blockIdx.y, j0 = blockIdx.x * 64, t = threadIdx.x;
    for (int dc = 0; dc < 4; ++dc) {
        int dd = t & 63, rg = t >> 6;
        float wv = cqw[dc * 64 + dd];
        for (int r = rg; r < 64; r += 4) {
            float v = q[((size_t)b * LQ + j0 + r) * DD + dc * 64 + dd];
            qw16[((size_t)b * LQ + j0 + r) * DD + dc * 64 + dd] = f2b(v * wv);
            T[dd][r] = v;
        }
        __syncthreads();
        int jj = t & 63;
        for (int dw = t >> 6; dw < 64; dw += 4)
            qT16[((size_t)b * DD + dc * 64 + dw) * LQ + j0 + jj] = f2b(T[dw][jj]);
        __syncthreads();
    }
}

// ---------- k1: S = c @ (q*cqw)^T + s0 + s1 (MFMA), store bf16 S + col partials ----
__global__ __launch_bounds__(256) void k1_S(
        const short* __restrict__ c16, const short* __restrict__ qw16,
        const float* __restrict__ cmask,
        const float* __restrict__ s0c, const float* __restrict__ s1q,
        short* __restrict__ Sb, float* __restrict__ pm, float* __restrict__ ps) {
    __shared__ short As[128 * 64];
    __shared__ short Bs[128 * 64];
    int b  = blockIdx.z;
    int i0 = blockIdx.x * 128;
    int j0 = blockIdx.y * 128;
    int t = threadIdx.x;
    int l = t & 63, w = t >> 6;
    int wr = w >> 1, wc = w & 1;

    f32x4 acc[4][4];
    #pragma unroll
    for (int m = 0; m < 4; ++m)
        #pragma unroll
        for (int n = 0; n < 4; ++n) acc[m][n] = (f32x4){0.f, 0.f, 0.f, 0.f};

    const short* Ag = c16  + ((size_t)b * LC + i0) * DD;
    const short* Bg = qw16 + ((size_t)b * LQ + j0) * DD;
    int lrow = l >> 3;                      // row within 8-row chunk
    int lcolsw = ((l & 7) ^ lrow) * 8;      // swizzled source col (bf16 elems)

    for (int kt = 0; kt < DD; kt += 64) {
        __syncthreads();
        #pragma unroll
        for (int r = 0; r < 4; ++r) {
            int chunk = r * 4 + w;          // 0..15, uniform per wave
            int row = chunk * 8 + lrow;     // 0..127
            gload_lds16(Ag + (size_t)row * DD + kt + lcolsw, As + chunk * 512);
            gload_lds16(Bg + (size_t)row * DD + kt + lcolsw, Bs + chunk * 512);
        }
        __syncthreads();
        #pragma unroll
        for (int kf = 0; kf < 2; ++kf) {
            bf16x8 a[4], bb[4];
            #pragma unroll
            for (int m = 0; m < 4; ++m) {
                int row = wr * 64 + m * 16 + (l & 15);
                int byte = row * 128 + kf * 64 + (l >> 4) * 16;
                a[m] = *(const bf16x8*)((const char*)As + (byte ^ ((row & 7) << 4)));
            }
            #pragma unroll
            for (int n = 0; n < 4; ++n) {
                int row = wc * 64 + n * 16 + (l & 15);
                int byte = row * 128 + kf * 64 + (l >> 4) * 16;
                bb[n] = *(const bf16x8*)((const char*)Bs + (byte ^ ((row & 7) << 4)));
            }
            #pragma unroll
            for (int m = 0; m < 4; ++m)
                #pragma unroll
                for (int n = 0; n < 4; ++n)
                    acc[m][n] = MFMA16(a[m], bb[n], acc[m][n]);
        }
    }

    // epilogue: add s0c + s1q, round to bf16, store S, fused column partial stats
    int jb = j0 + wc * 64;
    float s1v[4];
    #pragma unroll
    for (int n = 0; n < 4; ++n) s1v[n] = s1q[b * LQ + jb + n * 16 + (l & 15)];
    float s0r[4][4], cmr[4][4];
    #pragma unroll
    for (int m = 0; m < 4; ++m)
        #pragma unroll
        for (int reg = 0; reg < 4; ++reg) {
            int il = wr * 64 + m * 16 + (l >> 4) * 4 + reg;
            s0r[m][reg] = s0c[b * LC + i0 + il];
            cmr[m][reg] = cmask[b * LC + i0 + il];
        }
    #pragma unroll
    for (int m = 0; m < 4; ++m)
        #pragma unroll
        for (int n = 0; n < 4; ++n)
            #pragma unroll
            for (int reg = 0; reg < 4; ++reg) {
                float v = acc[m][n][reg] + s0r[m][reg] + s1v[n];
                short sb = f2b(v);
                int il = wr * 64 + m * 16 + (l >> 4) * 4 + reg;
                Sb[((size_t)b * LC + i0 + il) * LQ + jb + n * 16 + (l & 15)] = sb;
                acc[m][n][reg] = b2f(sb);
            }
    #pragma unroll
    for (int n = 0; n < 4; ++n) {
        float x2v[16];
        float mx = NEGINF;
        #pragma unroll
        for (int m = 0; m < 4; ++m)
            #pragma unroll
            for (int reg = 0; reg < 4; ++reg) {
                float cm = cmr[m][reg];
                float x2 = acc[m][n][reg] * cm + (1.f - cm) * NEGINF;
                x2v[m * 4 + reg] = x2;
                mx = fmaxf(mx, x2);
            }
        float ss = 0.f;
        #pragma unroll
        for (int e = 0; e < 16; ++e) ss += __expf(x2v[e] - mx);
        #pragma unroll
        for (int off = 16; off <= 32; off <<= 1) {
            float om = __shfl_xor(mx, off, 64);
            float os = __shfl_xor(ss, off, 64);
            float nm = fmaxf(mx, om);
            ss = ss * __expf(mx - nm) + os * __expf(om - nm);
            mx = nm;
        }
        if (l < 16) {
            size_t idx = ((size_t)b * 32 + blockIdx.x * 2 + wr) * LQ + jb + n * 16 + l;
            pm[idx] = mx;
            ps[idx] = ss;
        }
    }
}

// ---------- k2b: combine 32 chunk partials -> colC = m + log(Z) ----------
__global__ __launch_bounds__(256) void k2b_colstats(
        const float* __restrict__ pm, const float* __restrict__ ps,
        float* __restrict__ colC) {
    int b = blockIdx.x, t = threadIdx.x;
    float m = NEGINF, s = 0.f;
    for (int ch = 0; ch < 32; ++ch) {
        float pmv = pm[((size_t)b * 32 + ch) * LQ + t];
        float psv = ps[((size_t)b * 32 + ch) * LQ + t];
        float mn = fmaxf(m, pmv);
        s = s * __expf(m - mn) + psv * __expf(pmv - mn);
        m = mn;
    }
    colC[b * LQ + t] = m + logf(s);
}

// ---------- k3: A2CT[b,d,j] = sum_i c[i,d] * P2[i,j]  (MFMA GEMM, exp fused) ----
#define K3S 72   // padded LDS row stride (shorts); 144 B = 16B aligned, bank-friendly
__global__ __launch_bounds__(256) void k3_A2C(
        const short* __restrict__ c16, const short* __restrict__ Sb,
        const float* __restrict__ cmask, const float* __restrict__ colC,
        short* __restrict__ A2CT) {
    __shared__ short As[128 * K3S];   // [d][i]
    __shared__ short Bs[128 * K3S];   // [j][i]
    int b  = blockIdx.z;
    int d0 = blockIdx.x * 128;
    int j0 = blockIdx.y * 128;
    int t = threadIdx.x, l = t & 63, w = t >> 6;
    int wr = w >> 1, wc = w & 1;

    f32x4 acc[4][4];
    #pragma unroll
    for (int m = 0; m < 4; ++m)
        #pragma unroll
        for (int n = 0; n < 4; ++n) acc[m][n] = (f32x4){0.f, 0.f, 0.f, 0.f};

    int ii = t >> 2;            // 0..63 : i within K-step
    int c4 = (t & 3) * 8;       // 16B sub-chunk

    for (int k0 = 0; k0 < LC; k0 += 64) {
        __syncthreads();
        float cm = cmask[b * LC + k0 + ii];
        float negc = (1.f - cm) * NEGINF;
        #pragma unroll
        for (int e = 0; e < 4; ++e) {
            int dpos = c4 + e * 32;   // 0..127
            bf16x8 av = *(const bf16x8*)(c16 +
                    ((size_t)(b * LC + k0 + ii)) * DD + d0 + dpos);
            #pragma unroll
            for (int g = 0; g < 8; ++g) As[(dpos + g) * K3S + ii] = av[g];

            int jpos = c4 + e * 32;
            bf16x8 sv8 = *(const bf16x8*)(Sb +
                    ((size_t)(b * LC + k0 + ii)) * LQ + j0 + jpos);
            float4 cc0 = *(const float4*)(colC + b * LQ + j0 + jpos);
            float4 cc1 = *(const float4*)(colC + b * LQ + j0 + jpos + 4);
            float ccv[8] = {cc0.x, cc0.y, cc0.z, cc0.w, cc1.x, cc1.y, cc1.z, cc1.w};
            #pragma unroll
            for (int g = 0; g < 8; ++g) {
                float p = __expf(fmaf(b2f(sv8[g]), cm, negc) - ccv[g]);
                Bs[(jpos + g) * K3S + ii] = f2b(p);
            }
        }
        __syncthreads();
        #pragma unroll
        for (int kf = 0; kf < 2; ++kf) {
            bf16x8 a[4], bb[4];
            #pragma unroll
            for (int m = 0; m < 4; ++m) {
                int row = wr * 64 + m * 16 + (l & 15);
                a[m] = *(const bf16x8*)((const char*)As +
                        row * (K3S * 2) + kf * 64 + (l >> 4) * 16);
            }
            #pragma unroll
            for (int n = 0; n < 4; ++n) {
                int row = wc * 64 + n * 16 + (l & 15);
                bb[n] = *(const bf16x8*)((const char*)Bs +
                        row * (K3S * 2) + kf * 64 + (l >> 4) * 16);
            }
            #pragma unroll
            for (int m = 0; m < 4; ++m)
                #pragma unroll
                for (int n = 0; n < 4; ++n)
                    acc[m][n] = MFMA16(a[m], bb[n], acc[m][n]);
        }
    }
    // D[d][j]: write A2CT bf16; lanes (l&15) cover 16 consecutive j
    #pragma unroll
    for (int m = 0; m < 4; ++m)
        #pragma unroll
        for (int n = 0; n < 4; ++n)
            #pragma unroll
            for (int reg = 0; reg < 4; ++reg) {
                int d = d0 + wr * 64 + m * 16 + (l >> 4) * 4 + reg;
                int j = j0 + wc * 64 + n * 16 + (l & 15);
                A2CT[((size_t)b * DD + d) * LQ + j] = f2b(acc[m][n][reg]);
            }
}

// ---------- k4: row softmax (q_mask) + C2Q=S1@q + Q2C=S1@A2C + fused epilogue ----
__global__ __launch_bounds__(256) void k4_out(
        const short* __restrict__ Sb, const short* __restrict__ qT16,
        const short* __restrict__ A2CT, const float* __restrict__ c,
        const float* __restrict__ qmask, float* __restrict__ out) {
    __shared__ short P1[64 * 256];   // XOR-swizzled rows
    int b = blockIdx.y, i0 = blockIdx.x * 64;
    int t = threadIdx.x, l = t & 63, w = t >> 6;

    float4 qm4 = *(const float4*)(qmask + b * LQ + l * 4);
    for (int rr = 0; rr < 16; ++rr) {
        int r = rr * 4 + w;
        short4 s4 = *(const short4*)(Sb + ((size_t)b * LC + i0 + r) * LQ + l * 4);
        float x0 = b2f(s4.x) * qm4.x + (1.f - qm4.x) * NEGINF;
        float x1 = b2f(s4.y) * qm4.y + (1.f - qm4.y) * NEGINF;
        float x2 = b2f(s4.z) * qm4.z + (1.f - qm4.z) * NEGINF;
        float x3 = b2f(s4.w) * qm4.w + (1.f - qm4.w) * NEGINF;
        float mx = fmaxf(fmaxf(x0, x1), fmaxf(x2, x3));
        #pragma unroll
        for (int o = 32; o > 0; o >>= 1) mx = fmaxf(mx, __shfl_xor(mx, o, 64));
        float p0 = __expf(x0 - mx), p1 = __expf(x1 - mx);
        float p2 = __expf(x2 - mx), p3 = __expf(x3 - mx);
        float Z = p0 + p1 + p2 + p3;
        #pragma unroll
        for (int o = 32; o > 0; o >>= 1) Z += __shfl_xor(Z, o, 64);
        float inv = 1.f / Z;
        ushort4 pk;
        pk.x = (unsigned short)f2b(p0 * inv);
        pk.y = (unsigned short)f2b(p1 * inv);
        pk.z = (unsigned short)f2b(p2 * inv);
        pk.w = (unsigned short)f2b(p3 * inv);
        int byte = r * 512 + l * 8;
        *(ushort4*)((char*)P1 + (byte ^ ((r & 7) << 4))) = pk;
    }
    __syncthreads();

    f32x4 acc1[4][4], acc2[4][4];
    #pragma unroll
    for (int m = 0; m < 4; ++m)
        #pragma unroll
        for (int n = 0; n < 4; ++n) {
            acc1[m][n] = (f32x4){0.f, 0.f, 0.f, 0.f};
            acc2[m][n] = (f32x4){0.f, 0.f, 0.f, 0.f};
        }
    const short* qTb = qT16 + (size_t)b * DD * LQ;
    const short* aTb = A2CT + (size_t)b * DD * LQ;
    int d0w = w * 64;
    for (int kf = 0; kf < 8; ++kf) {
        bf16x8 a[4];
        #pragma unroll
        for (int m = 0; m < 4; ++m) {
            int row = m * 16 + (l & 15);
            int byte = row * 512 + kf * 64 + (l >> 4) * 16;
            a[m] = *(const bf16x8*)((const char*)P1 + (byte ^ ((row & 7) << 4)));
        }
        #pragma unroll
        for (int n = 0; n < 4; ++n) {
            int d = d0w + n * 16 + (l & 15);
            size_t off = (size_t)d * LQ + kf * 32 + (l >> 4) * 8;
            bf16x8 bq = *(const bf16x8*)(qTb + off);
            bf16x8 ba = *(const bf16x8*)(aTb + off);
            #pragma unroll
            for (int m = 0; m < 4; ++m) {
                acc1[m][n] = MFMA16(a[m], bq, acc1[m][n]);
                acc2[m][n] = MFMA16(a[m], ba, acc2[m][n]);
            }
        }
    }
    #pragma unroll
    for (int m = 0; m < 4; ++m)
        #pragma unroll
        for (int n = 0; n < 4; ++n)
            #pragma unroll
            for (int reg = 0; reg < 4; ++reg) {
                int i = i0 + m * 16 + (l >> 4) * 4 + reg;
                int d = d0w + n * 16 + (l & 15);
                float cv = c[((size_t)b * LC + i) * DD + d];
                size_t ob = ((size_t)b * LC + i) * (size_t)(4 * DD);
                float v1 = acc1[m][n][reg], v2 = acc2[m][n][reg];
                out[ob + d]           = cv;
                out[ob + 256 + d]     = v1;
                out[ob + 512 + d]     = cv * v1;
                out[ob + 768 + d]     = cv * v2;
            }
}

extern "C" void kernel_launch(void* const* d_in, const int* in_sizes, int n_in,
                              void* d_out, int out_size, void* d_ws, size_t ws_size,
                              hipStream_t stream) {
    const float* c     = (const float*)d_in[0];
    const float* q     = (const float*)d_in[1];
    const float* cmask = (const float*)d_in[2];
    const float* qmask = (const float*)d_in[3];
    const float* cqw   = (const float*)d_in[4];
    const float* c_w   = (const float*)d_in[5];
    const float* q_w   = (const float*)d_in[6];
    const float* bias  = (const float*)d_in[7];
    float* out = (float*)d_out;

    char* w = (char*)d_ws;
    short* Sb    = (short*)(w);                  // 16,777,216 B
    short* c16   = (short*)(w + 16777216);       // 16,777,216 B
    short* qw16  = (short*)(w + 33554432);       //  2,097,152 B
    short* qT16  = (short*)(w + 35651584);       //  2,097,152 B
    short* A2CT  = (short*)(w + 37748736);       //  2,097,152 B
    float* s0c   = (float*)(w + 39845888);       //    131,072 B
    float* s1q   = (float*)(w + 39976960);       //     16,384 B
    float* pm    = (float*)(w + 39993344);       //    524,288 B
    float* ps    = (float*)(w + 40517632);       //    524,288 B
    float* colC  = (float*)(w + 41041920);       //     16,384 B  (end 41,058,304)

    k0_rowdots<<<dim3((NB * LC + NB * LQ) / 4), dim3(256), 0, stream>>>(
        c, q, c_w, q_w, bias, s0c, s1q);
    prep_c16<<<dim3(NB * LC * DD / 1024), dim3(256), 0, stream>>>(c, c16);
    prep_q<<<dim3(LQ / 64, NB), dim3(256), 0, stream>>>(q, cqw, qw16, qT16);
    k1_S<<<dim3(LC / 128, LQ / 128, NB), dim3(256), 0, stream>>>(
        c16, qw16, cmask, s0c, s1q, Sb, pm, ps);
    k2b_colstats<<<dim3(NB), dim3(256), 0, stream>>>(pm, ps, colC);
    k3_A2C<<<dim3(DD / 128, LQ / 128, NB), dim3(256), 0, stream>>>(
        c16, Sb, cmask, colC, A2CT);
    k4_out<<<dim3(LC / 64, NB), dim3(256), 0, stream>>>(
        Sb, qT16, A2CT, c, qmask, out);
}

// Round 4
// 129.215 us; speedup vs baseline: 6.1576x; 1.3783x over previous
//
#include <hip/hip_runtime.h>
#include <hip/hip_bf16.h>

#define NB 16
#define LC 2048
#define LQ 256
#define DD 256
#define NEGINF -1e30f

typedef __attribute__((ext_vector_type(8))) short bf16x8;
typedef __attribute__((ext_vector_type(4))) float f32x4;

#define MFMA16(a, b, c) __builtin_amdgcn_mfma_f32_16x16x32_bf16((a), (b), (c), 0, 0, 0)

typedef const unsigned int __attribute__((address_space(1))) glb_u32;
typedef unsigned int __attribute__((address_space(3))) lds_u32;

__device__ __forceinline__ void gload_lds16(const void* g, void* l) {
    __builtin_amdgcn_global_load_lds((glb_u32*)g, (lds_u32*)l, 16, 0, 0);
}

__device__ __forceinline__ short f2b(float x) {
    unsigned u = __float_as_uint(x);
    unsigned r = (u + 0x7fffu + ((u >> 16) & 1u)) >> 16;
    return (short)r;
}
__device__ __forceinline__ float b2f(short s) {
    return __uint_as_float(((unsigned)(unsigned short)s) << 16);
}

// ---------- prep_c: one pass over c -> c16 (bf16) + s0c row-dots ----------
__global__ __launch_bounds__(256) void prep_c(
        const float* __restrict__ c, const float* __restrict__ c_w,
        short* __restrict__ c16, float* __restrict__ s0c) {
    int row = blockIdx.x * 8 + (threadIdx.x >> 5);
    int k = threadIdx.x & 31;               // 32 lanes per row, 8 floats each
    const float* src = c + (size_t)row * DD + k * 8;
    float4 v0 = *(const float4*)(src);
    float4 v1 = *(const float4*)(src + 4);
    float4 w0 = *(const float4*)(c_w + k * 8);
    float4 w1 = *(const float4*)(c_w + k * 8 + 4);
    float s = v0.x * w0.x + v0.y * w0.y + v0.z * w0.z + v0.w * w0.w
            + v1.x * w1.x + v1.y * w1.y + v1.z * w1.z + v1.w * w1.w;
    #pragma unroll
    for (int o = 16; o > 0; o >>= 1) s += __shfl_xor(s, o, 64);
    if (k == 0) s0c[row] = s;
    ushort4 o0, o1;
    o0.x = (unsigned short)f2b(v0.x); o0.y = (unsigned short)f2b(v0.y);
    o0.z = (unsigned short)f2b(v0.z); o0.w = (unsigned short)f2b(v0.w);
    o1.x = (unsigned short)f2b(v1.x); o1.y = (unsigned short)f2b(v1.y);
    o1.z = (unsigned short)f2b(v1.z); o1.w = (unsigned short)f2b(v1.w);
    ushort4* dst = (ushort4*)(c16 + (size_t)row * DD + k * 8);
    dst[0] = o0;
    dst[1] = o1;
}

// ---------- prep_q: one pass over q -> qw16 = bf16(q*cqw), qT16 = bf16(q)^T, s1q ----
__global__ __launch_bounds__(256) void prep_q(
        const float* __restrict__ q, const float* __restrict__ cqw,
        const float* __restrict__ q_w, const float* __restrict__ bias,
        short* __restrict__ qw16, short* __restrict__ qT16,
        float* __restrict__ s1q) {
    __shared__ float T[64][65];
    int b = blockIdx.y, j0 = blockIdx.x * 64, t = threadIdx.x;
    int dd = t & 63, rg = t >> 6;
    float acc[16];
    #pragma unroll
    for (int i = 0; i < 16; ++i) acc[i] = 0.f;
    for (int dc = 0; dc < 4; ++dc) {
        float wv = cqw[dc * 64 + dd];
        float qwv = q_w[dc * 64 + dd];
        #pragma unroll
        for (int rr = 0; rr < 16; ++rr) {
            int r = rg + 4 * rr;
            float v = q[((size_t)b * LQ + j0 + r) * DD + dc * 64 + dd];
            qw16[((size_t)b * LQ + j0 + r) * DD + dc * 64 + dd] = f2b(v * wv);
            acc[rr] += v * qwv;
            T[dd][r] = v;
        }
        __syncthreads();
        int jj = t & 63;
        for (int dw = t >> 6; dw < 64; dw += 4)
            qT16[((size_t)b * DD + dc * 64 + dw) * LQ + j0 + jj] = f2b(T[dw][jj]);
        __syncthreads();
    }
    float bv = bias[0];
    #pragma unroll
    for (int rr = 0; rr < 16; ++rr) {
        float s = acc[rr];
        #pragma unroll
        for (int o = 32; o > 0; o >>= 1) s += __shfl_xor(s, o, 64);
        if (dd == 0) s1q[b * LQ + j0 + rg + 4 * rr] = s + bv;
    }
}

// ---------- k1: S = c @ (q*cqw)^T + s0 + s1 (MFMA), store bf16 S + col partials ----
__global__ __launch_bounds__(256) void k1_S(
        const short* __restrict__ c16, const short* __restrict__ qw16,
        const float* __restrict__ cmask,
        const float* __restrict__ s0c, const float* __restrict__ s1q,
        short* __restrict__ Sb, float* __restrict__ pm, float* __restrict__ ps) {
    __shared__ short As[128 * 64];
    __shared__ short Bs[128 * 64];
    int b  = blockIdx.z;
    int i0 = blockIdx.x * 128;
    int j0 = blockIdx.y * 128;
    int t = threadIdx.x;
    int l = t & 63, w = t >> 6;
    int wr = w >> 1, wc = w & 1;

    f32x4 acc[4][4];
    #pragma unroll
    for (int m = 0; m < 4; ++m)
        #pragma unroll
        for (int n = 0; n < 4; ++n) acc[m][n] = (f32x4){0.f, 0.f, 0.f, 0.f};

    const short* Ag = c16  + ((size_t)b * LC + i0) * DD;
    const short* Bg = qw16 + ((size_t)b * LQ + j0) * DD;
    int lrow = l >> 3;                      // row within 8-row chunk
    int lcolsw = ((l & 7) ^ lrow) * 8;      // swizzled source col (bf16 elems)

    for (int kt = 0; kt < DD; kt += 64) {
        __syncthreads();
        #pragma unroll
        for (int r = 0; r < 4; ++r) {
            int chunk = r * 4 + w;          // 0..15, uniform per wave
            int row = chunk * 8 + lrow;     // 0..127
            gload_lds16(Ag + (size_t)row * DD + kt + lcolsw, As + chunk * 512);
            gload_lds16(Bg + (size_t)row * DD + kt + lcolsw, Bs + chunk * 512);
        }
        __syncthreads();
        #pragma unroll
        for (int kf = 0; kf < 2; ++kf) {
            bf16x8 a[4], bb[4];
            #pragma unroll
            for (int m = 0; m < 4; ++m) {
                int row = wr * 64 + m * 16 + (l & 15);
                int byte = row * 128 + kf * 64 + (l >> 4) * 16;
                a[m] = *(const bf16x8*)((const char*)As + (byte ^ ((row & 7) << 4)));
            }
            #pragma unroll
            for (int n = 0; n < 4; ++n) {
                int row = wc * 64 + n * 16 + (l & 15);
                int byte = row * 128 + kf * 64 + (l >> 4) * 16;
                bb[n] = *(const bf16x8*)((const char*)Bs + (byte ^ ((row & 7) << 4)));
            }
            #pragma unroll
            for (int m = 0; m < 4; ++m)
                #pragma unroll
                for (int n = 0; n < 4; ++n)
                    acc[m][n] = MFMA16(a[m], bb[n], acc[m][n]);
        }
    }

    // epilogue: add s0c + s1q, round to bf16, store S, fused column partial stats
    int jb = j0 + wc * 64;
    float s1v[4];
    #pragma unroll
    for (int n = 0; n < 4; ++n) s1v[n] = s1q[b * LQ + jb + n * 16 + (l & 15)];
    float s0r[4][4], cmr[4][4];
    #pragma unroll
    for (int m = 0; m < 4; ++m)
        #pragma unroll
        for (int reg = 0; reg < 4; ++reg) {
            int il = wr * 64 + m * 16 + (l >> 4) * 4 + reg;
            s0r[m][reg] = s0c[b * LC + i0 + il];
            cmr[m][reg] = cmask[b * LC + i0 + il];
        }
    #pragma unroll
    for (int m = 0; m < 4; ++m)
        #pragma unroll
        for (int n = 0; n < 4; ++n)
            #pragma unroll
            for (int reg = 0; reg < 4; ++reg) {
                float v = acc[m][n][reg] + s0r[m][reg] + s1v[n];
                short sb = f2b(v);
                int il = wr * 64 + m * 16 + (l >> 4) * 4 + reg;
                Sb[((size_t)b * LC + i0 + il) * LQ + jb + n * 16 + (l & 15)] = sb;
                acc[m][n][reg] = b2f(sb);
            }
    #pragma unroll
    for (int n = 0; n < 4; ++n) {
        float x2v[16];
        float mx = NEGINF;
        #pragma unroll
        for (int m = 0; m < 4; ++m)
            #pragma unroll
            for (int reg = 0; reg < 4; ++reg) {
                float cm = cmr[m][reg];
                float x2 = acc[m][n][reg] * cm + (1.f - cm) * NEGINF;
                x2v[m * 4 + reg] = x2;
                mx = fmaxf(mx, x2);
            }
        float ss = 0.f;
        #pragma unroll
        for (int e = 0; e < 16; ++e) ss += __expf(x2v[e] - mx);
        #pragma unroll
        for (int off = 16; off <= 32; off <<= 1) {
            float om = __shfl_xor(mx, off, 64);
            float os = __shfl_xor(ss, off, 64);
            float nm = fmaxf(mx, om);
            ss = ss * __expf(mx - nm) + os * __expf(om - nm);
            mx = nm;
        }
        if (l < 16) {
            size_t idx = ((size_t)b * 32 + blockIdx.x * 2 + wr) * LQ + jb + n * 16 + l;
            pm[idx] = mx;
            ps[idx] = ss;
        }
    }
}

// ---------- k3: split-K partials of A2CT[d,j] = sum_i c[i,d] * P2[i,j] ----------
#define K3S 72   // padded LDS row stride (shorts)
__global__ __launch_bounds__(256) void k3_A2C(
        const short* __restrict__ c16, const short* __restrict__ Sb,
        const float* __restrict__ cmask,
        const float* __restrict__ pm, const float* __restrict__ ps,
        float* __restrict__ p3) {
    __shared__ short As[128 * K3S];   // [d][i]
    __shared__ short Bs[128 * K3S];   // [j][i]
    __shared__ float colCs[128];
    int b  = blockIdx.z;
    int ks = blockIdx.y;
    int d0 = (blockIdx.x >> 1) * 128;
    int j0 = (blockIdx.x & 1) * 128;
    int t = threadIdx.x, l = t & 63, w = t >> 6;
    int wr = w >> 1, wc = w & 1;

    // fused colC = m + log(Z) for this block's 128 columns
    if (t < 128) {
        float m = NEGINF, s = 0.f;
        for (int ch = 0; ch < 32; ++ch) {
            float pmv = pm[((size_t)b * 32 + ch) * LQ + j0 + t];
            float psv = ps[((size_t)b * 32 + ch) * LQ + t + j0];
            float mn = fmaxf(m, pmv);
            s = s * __expf(m - mn) + psv * __expf(pmv - mn);
            m = mn;
        }
        colCs[t] = m + logf(s);
    }
    __syncthreads();

    f32x4 acc[4][4];
    #pragma unroll
    for (int m = 0; m < 4; ++m)
        #pragma unroll
        for (int n = 0; n < 4; ++n) acc[m][n] = (f32x4){0.f, 0.f, 0.f, 0.f};

    int ii = t >> 2;            // 0..63 : i within K-step
    int c4 = (t & 3) * 8;       // 16B sub-chunk

    for (int k0 = ks * 256; k0 < ks * 256 + 256; k0 += 64) {
        __syncthreads();
        float cm = cmask[b * LC + k0 + ii];
        float negc = (1.f - cm) * NEGINF;
        #pragma unroll
        for (int e = 0; e < 4; ++e) {
            int dpos = c4 + e * 32;   // 0..127
            bf16x8 av = *(const bf16x8*)(c16 +
                    ((size_t)(b * LC + k0 + ii)) * DD + d0 + dpos);
            #pragma unroll
            for (int g = 0; g < 8; ++g) As[(dpos + g) * K3S + ii] = av[g];

            int jpos = c4 + e * 32;
            bf16x8 sv8 = *(const bf16x8*)(Sb +
                    ((size_t)(b * LC + k0 + ii)) * LQ + j0 + jpos);
            #pragma unroll
            for (int g = 0; g < 8; ++g) {
                float p = __expf(fmaf(b2f(sv8[g]), cm, negc) - colCs[jpos + g]);
                Bs[(jpos + g) * K3S + ii] = f2b(p);
            }
        }
        __syncthreads();
        #pragma unroll
        for (int kf = 0; kf < 2; ++kf) {
            bf16x8 a[4], bb[4];
            #pragma unroll
            for (int m = 0; m < 4; ++m) {
                int row = wr * 64 + m * 16 + (l & 15);
                a[m] = *(const bf16x8*)((const char*)As +
                        row * (K3S * 2) + kf * 64 + (l >> 4) * 16);
            }
            #pragma unroll
            for (int n = 0; n < 4; ++n) {
                int row = wc * 64 + n * 16 + (l & 15);
                bb[n] = *(const bf16x8*)((const char*)Bs +
                        row * (K3S * 2) + kf * 64 + (l >> 4) * 16);
            }
            #pragma unroll
            for (int m = 0; m < 4; ++m)
                #pragma unroll
                for (int n = 0; n < 4; ++n)
                    acc[m][n] = MFMA16(a[m], bb[n], acc[m][n]);
        }
    }
    // write fp32 partial tile [128 d][128 j]
    float* P = p3 + (((size_t)b * 8 + ks) * 4 + blockIdx.x) * 16384;
    #pragma unroll
    for (int m = 0; m < 4; ++m)
        #pragma unroll
        for (int n = 0; n < 4; ++n)
            #pragma unroll
            for (int reg = 0; reg < 4; ++reg) {
                int ld = wr * 64 + m * 16 + (l >> 4) * 4 + reg;
                int lj = wc * 64 + n * 16 + (l & 15);
                P[ld * 128 + lj] = acc[m][n][reg];
            }
}

// ---------- k3r: reduce 8 K-split partials -> bf16 A2CT ----------
__global__ __launch_bounds__(256) void k3r_reduce(
        const float* __restrict__ p3, short* __restrict__ A2CT) {
    int b = blockIdx.y;
    int linear = blockIdx.x * 256 + threadIdx.x;   // 0..16383
    int d = linear >> 6;
    int j4 = (linear & 63) * 4;
    int tile = (d >> 7) * 2 + (j4 >> 7);
    int ld = d & 127, lj = j4 & 127;
    const float* base = p3 + (((size_t)b * 8) * 4 + tile) * 16384 + ld * 128 + lj;
    float4 s = {0.f, 0.f, 0.f, 0.f};
    #pragma unroll
    for (int ks = 0; ks < 8; ++ks) {
        float4 v = *(const float4*)(base + (size_t)ks * 4 * 16384);
        s.x += v.x; s.y += v.y; s.z += v.z; s.w += v.w;
    }
    short4 o;
    o.x = f2b(s.x); o.y = f2b(s.y); o.z = f2b(s.z); o.w = f2b(s.w);
    *(short4*)(A2CT + ((size_t)b * DD + d) * LQ + j4) = o;
}

// ---------- k4: row softmax (q_mask) + C2Q=S1@q + Q2C=S1@A2C + fused epilogue ----
__global__ __launch_bounds__(256) void k4_out(
        const short* __restrict__ Sb, const short* __restrict__ qT16,
        const short* __restrict__ A2CT, const float* __restrict__ c,
        const float* __restrict__ qmask, float* __restrict__ out) {
    __shared__ short P1[64 * 256];   // XOR-swizzled rows
    int b = blockIdx.y, i0 = blockIdx.x * 64;
    int t = threadIdx.x, l = t & 63, w = t >> 6;

    float4 qm4 = *(const float4*)(qmask + b * LQ + l * 4);
    for (int rr = 0; rr < 16; ++rr) {
        int r = rr * 4 + w;
        short4 s4 = *(const short4*)(Sb + ((size_t)b * LC + i0 + r) * LQ + l * 4);
        float x0 = b2f(s4.x) * qm4.x + (1.f - qm4.x) * NEGINF;
        float x1 = b2f(s4.y) * qm4.y + (1.f - qm4.y) * NEGINF;
        float x2 = b2f(s4.z) * qm4.z + (1.f - qm4.z) * NEGINF;
        float x3 = b2f(s4.w) * qm4.w + (1.f - qm4.w) * NEGINF;
        float mx = fmaxf(fmaxf(x0, x1), fmaxf(x2, x3));
        #pragma unroll
        for (int o = 32; o > 0; o >>= 1) mx = fmaxf(mx, __shfl_xor(mx, o, 64));
        float p0 = __expf(x0 - mx), p1 = __expf(x1 - mx);
        float p2 = __expf(x2 - mx), p3v = __expf(x3 - mx);
        float Z = p0 + p1 + p2 + p3v;
        #pragma unroll
        for (int o = 32; o > 0; o >>= 1) Z += __shfl_xor(Z, o, 64);
        float inv = 1.f / Z;
        ushort4 pk;
        pk.x = (unsigned short)f2b(p0 * inv);
        pk.y = (unsigned short)f2b(p1 * inv);
        pk.z = (unsigned short)f2b(p2 * inv);
        pk.w = (unsigned short)f2b(p3v * inv);
        int byte = r * 512 + l * 8;
        *(ushort4*)((char*)P1 + (byte ^ ((r & 7) << 4))) = pk;
    }
    __syncthreads();

    f32x4 acc1[4][4], acc2[4][4];
    #pragma unroll
    for (int m = 0; m < 4; ++m)
        #pragma unroll
        for (int n = 0; n < 4; ++n) {
            acc1[m][n] = (f32x4){0.f, 0.f, 0.f, 0.f};
            acc2[m][n] = (f32x4){0.f, 0.f, 0.f, 0.f};
        }
    const short* qTb = qT16 + (size_t)b * DD * LQ;
    const short* aTb = A2CT + (size_t)b * DD * LQ;
    int d0w = w * 64;
    for (int kf = 0; kf < 8; ++kf) {
        bf16x8 a[4];
        #pragma unroll
        for (int m = 0; m < 4; ++m) {
            int row = m * 16 + (l & 15);
            int byte = row * 512 + kf * 64 + (l >> 4) * 16;
            a[m] = *(const bf16x8*)((const char*)P1 + (byte ^ ((row & 7) << 4)));
        }
        #pragma unroll
        for (int n = 0; n < 4; ++n) {
            int d = d0w + n * 16 + (l & 15);
            size_t off = (size_t)d * LQ + kf * 32 + (l >> 4) * 8;
            bf16x8 bq = *(const bf16x8*)(qTb + off);
            bf16x8 ba = *(const bf16x8*)(aTb + off);
            #pragma unroll
            for (int m = 0; m < 4; ++m) {
                acc1[m][n] = MFMA16(a[m], bq, acc1[m][n]);
                acc2[m][n] = MFMA16(a[m], ba, acc2[m][n]);
            }
        }
    }
    #pragma unroll
    for (int m = 0; m < 4; ++m)
        #pragma unroll
        for (int n = 0; n < 4; ++n)
            #pragma unroll
            for (int reg = 0; reg < 4; ++reg) {
                int i = i0 + m * 16 + (l >> 4) * 4 + reg;
                int d = d0w + n * 16 + (l & 15);
                float cv = c[((size_t)b * LC + i) * DD + d];
                size_t ob = ((size_t)b * LC + i) * (size_t)(4 * DD);
                float v1 = acc1[m][n][reg], v2 = acc2[m][n][reg];
                out[ob + d]           = cv;
                out[ob + 256 + d]     = v1;
                out[ob + 512 + d]     = cv * v1;
                out[ob + 768 + d]     = cv * v2;
            }
}

extern "C" void kernel_launch(void* const* d_in, const int* in_sizes, int n_in,
                              void* d_out, int out_size, void* d_ws, size_t ws_size,
                              hipStream_t stream) {
    const float* c     = (const float*)d_in[0];
    const float* q     = (const float*)d_in[1];
    const float* cmask = (const float*)d_in[2];
    const float* qmask = (const float*)d_in[3];
    const float* cqw   = (const float*)d_in[4];
    const float* c_w   = (const float*)d_in[5];
    const float* q_w   = (const float*)d_in[6];
    const float* bias  = (const float*)d_in[7];
    float* out = (float*)d_out;

    char* w = (char*)d_ws;
    short* Sb    = (short*)(w);                  // 16,777,216 B
    short* c16   = (short*)(w + 16777216);       // 16,777,216 B
    short* qw16  = (short*)(w + 33554432);       //  2,097,152 B
    short* qT16  = (short*)(w + 35651584);       //  2,097,152 B
    short* A2CT  = (short*)(w + 37748736);       //  2,097,152 B
    float* s0c   = (float*)(w + 39845888);       //    131,072 B
    float* s1q   = (float*)(w + 39976960);       //     16,384 B
    float* pm    = (float*)(w + 39993344);       //    524,288 B
    float* ps    = (float*)(w + 40517632);       //    524,288 B
    float* p3    = (float*)(w + 41041920);       // 33,554,432 B (end 74,596,352)

    prep_c<<<dim3(NB * LC / 8), dim3(256), 0, stream>>>(c, c_w, c16, s0c);
    prep_q<<<dim3(LQ / 64, NB), dim3(256), 0, stream>>>(
        q, cqw, q_w, bias, qw16, qT16, s1q);
    k1_S<<<dim3(LC / 128, LQ / 128, NB), dim3(256), 0, stream>>>(
        c16, qw16, cmask, s0c, s1q, Sb, pm, ps);
    k3_A2C<<<dim3(4, 8, NB), dim3(256), 0, stream>>>(
        c16, Sb, cmask, pm, ps, p3);
    k3r_reduce<<<dim3(64, NB), dim3(256), 0, stream>>>(p3, A2CT);
    k4_out<<<dim3(LC / 64, NB), dim3(256), 0, stream>>>(
        Sb, qT16, A2CT, c, qmask, out);
}

// Round 5
// 120.982 us; speedup vs baseline: 6.5767x; 1.0681x over previous
//
#include <hip/hip_runtime.h>
#include <hip/hip_bf16.h>

#define NB 16
#define LC 2048
#define LQ 256
#define DD 256
#define NEGINF -1e30f

typedef __attribute__((ext_vector_type(8))) short bf16x8;
typedef __attribute__((ext_vector_type(4))) float f32x4;

#define MFMA16(a, b, c) __builtin_amdgcn_mfma_f32_16x16x32_bf16((a), (b), (c), 0, 0, 0)

typedef const unsigned int __attribute__((address_space(1))) glb_u32;
typedef unsigned int __attribute__((address_space(3))) lds_u32;

__device__ __forceinline__ void gload_lds16(const void* g, void* l) {
    __builtin_amdgcn_global_load_lds((glb_u32*)g, (lds_u32*)l, 16, 0, 0);
}

__device__ __forceinline__ short f2b(float x) {
    unsigned u = __float_as_uint(x);
    unsigned r = (u + 0x7fffu + ((u >> 16) & 1u)) >> 16;
    return (short)r;
}
__device__ __forceinline__ float b2f(short s) {
    return __uint_as_float(((unsigned)(unsigned short)s) << 16);
}

// ---------- prep_c: one pass over c -> c16 (bf16) + s0c row-dots ----------
__global__ __launch_bounds__(256) void prep_c(
        const float* __restrict__ c, const float* __restrict__ c_w,
        short* __restrict__ c16, float* __restrict__ s0c) {
    int row = blockIdx.x * 8 + (threadIdx.x >> 5);
    int k = threadIdx.x & 31;               // 32 lanes per row, 8 floats each
    const float* src = c + (size_t)row * DD + k * 8;
    float4 v0 = *(const float4*)(src);
    float4 v1 = *(const float4*)(src + 4);
    float4 w0 = *(const float4*)(c_w + k * 8);
    float4 w1 = *(const float4*)(c_w + k * 8 + 4);
    float s = v0.x * w0.x + v0.y * w0.y + v0.z * w0.z + v0.w * w0.w
            + v1.x * w1.x + v1.y * w1.y + v1.z * w1.z + v1.w * w1.w;
    #pragma unroll
    for (int o = 16; o > 0; o >>= 1) s += __shfl_xor(s, o, 64);
    if (k == 0) s0c[row] = s;
    ushort4 o0, o1;
    o0.x = (unsigned short)f2b(v0.x); o0.y = (unsigned short)f2b(v0.y);
    o0.z = (unsigned short)f2b(v0.z); o0.w = (unsigned short)f2b(v0.w);
    o1.x = (unsigned short)f2b(v1.x); o1.y = (unsigned short)f2b(v1.y);
    o1.z = (unsigned short)f2b(v1.z); o1.w = (unsigned short)f2b(v1.w);
    ushort4* dst = (ushort4*)(c16 + (size_t)row * DD + k * 8);
    dst[0] = o0;
    dst[1] = o1;
}

// ---------- prep_q: one pass over q -> qw16 = bf16(q*cqw), qT16 = bf16(q)^T, s1q ----
__global__ __launch_bounds__(256) void prep_q(
        const float* __restrict__ q, const float* __restrict__ cqw,
        const float* __restrict__ q_w, const float* __restrict__ bias,
        short* __restrict__ qw16, short* __restrict__ qT16,
        float* __restrict__ s1q) {
    __shared__ float T[64][65];
    int b = blockIdx.y, j0 = blockIdx.x * 64, t = threadIdx.x;
    int dd = t & 63, rg = t >> 6;
    float acc[16];
    #pragma unroll
    for (int i = 0; i < 16; ++i) acc[i] = 0.f;
    for (int dc = 0; dc < 4; ++dc) {
        float wv = cqw[dc * 64 + dd];
        float qwv = q_w[dc * 64 + dd];
        #pragma unroll
        for (int rr = 0; rr < 16; ++rr) {
            int r = rg + 4 * rr;
            float v = q[((size_t)b * LQ + j0 + r) * DD + dc * 64 + dd];
            qw16[((size_t)b * LQ + j0 + r) * DD + dc * 64 + dd] = f2b(v * wv);
            acc[rr] += v * qwv;
            T[dd][r] = v;
        }
        __syncthreads();
        int jj = t & 63;
        for (int dw = t >> 6; dw < 64; dw += 4)
            qT16[((size_t)b * DD + dc * 64 + dw) * LQ + j0 + jj] = f2b(T[dw][jj]);
        __syncthreads();
    }
    float bv = bias[0];
    #pragma unroll
    for (int rr = 0; rr < 16; ++rr) {
        float s = acc[rr];
        #pragma unroll
        for (int o = 32; o > 0; o >>= 1) s += __shfl_xor(s, o, 64);
        if (dd == 0) s1q[b * LQ + j0 + rg + 4 * rr] = s + bv;
    }
}

// ---------- k1: S tile [128 x 256] = c @ (q*cqw)^T + s0 + s1; bf16 S + col partials
// ---------- + fused row-softmax stats rowC = m + log(Z) (8 waves, 512 threads)
__global__ __launch_bounds__(512) void k1_S(
        const short* __restrict__ c16, const short* __restrict__ qw16,
        const float* __restrict__ cmask, const float* __restrict__ qmask,
        const float* __restrict__ s0c, const float* __restrict__ s1q,
        short* __restrict__ Sb, float* __restrict__ pm, float* __restrict__ ps,
        float* __restrict__ rowC) {
    __shared__ short As[128 * 64];
    __shared__ short Bs[256 * 64];
    __shared__ float rmLds[128 * 4];
    __shared__ float rsLds[128 * 4];
    int b  = blockIdx.y;
    int i0 = blockIdx.x * 128;
    int t = threadIdx.x;
    int l = t & 63, w = t >> 6;
    int wr = w >> 2, wc = w & 3;

    f32x4 acc[4][4];
    #pragma unroll
    for (int m = 0; m < 4; ++m)
        #pragma unroll
        for (int n = 0; n < 4; ++n) acc[m][n] = (f32x4){0.f, 0.f, 0.f, 0.f};

    const short* Ag = c16  + ((size_t)b * LC + i0) * DD;
    const short* Bg = qw16 + ((size_t)b * LQ) * DD;
    int lrow = l >> 3;                      // row within 8-row chunk
    int lcolsw = ((l & 7) ^ lrow) * 8;      // swizzled source col (bf16 elems)

    for (int kt = 0; kt < DD; kt += 64) {
        __syncthreads();
        #pragma unroll
        for (int r = 0; r < 2; ++r) {       // A: 16 chunks of 1KB
            int chunk = r * 8 + w;
            int row = chunk * 8 + lrow;
            gload_lds16(Ag + (size_t)row * DD + kt + lcolsw, As + chunk * 512);
        }
        #pragma unroll
        for (int r = 0; r < 4; ++r) {       // B: 32 chunks of 1KB
            int chunk = r * 8 + w;
            int row = chunk * 8 + lrow;
            gload_lds16(Bg + (size_t)row * DD + kt + lcolsw, Bs + chunk * 512);
        }
        __syncthreads();
        #pragma unroll
        for (int kf = 0; kf < 2; ++kf) {
            bf16x8 a[4], bb[4];
            #pragma unroll
            for (int m = 0; m < 4; ++m) {
                int row = wr * 64 + m * 16 + (l & 15);
                int byte = row * 128 + kf * 64 + (l >> 4) * 16;
                a[m] = *(const bf16x8*)((const char*)As + (byte ^ ((row & 7) << 4)));
            }
            #pragma unroll
            for (int n = 0; n < 4; ++n) {
                int row = wc * 64 + n * 16 + (l & 15);
                int byte = row * 128 + kf * 64 + (l >> 4) * 16;
                bb[n] = *(const bf16x8*)((const char*)Bs + (byte ^ ((row & 7) << 4)));
            }
            #pragma unroll
            for (int m = 0; m < 4; ++m)
                #pragma unroll
                for (int n = 0; n < 4; ++n)
                    acc[m][n] = MFMA16(a[m], bb[n], acc[m][n]);
        }
    }

    // epilogue: add s0c + s1q, round to bf16, store S
    float s1v[4], qmv[4], negq[4];
    #pragma unroll
    for (int n = 0; n < 4; ++n) {
        int j = wc * 64 + n * 16 + (l & 15);
        s1v[n] = s1q[b * LQ + j];
        qmv[n] = qmask[b * LQ + j];
        negq[n] = (1.f - qmv[n]) * NEGINF;
    }
    float s0r[4][4], cmr[4][4];
    #pragma unroll
    for (int m = 0; m < 4; ++m)
        #pragma unroll
        for (int reg = 0; reg < 4; ++reg) {
            int il = wr * 64 + m * 16 + (l >> 4) * 4 + reg;
            s0r[m][reg] = s0c[b * LC + i0 + il];
            cmr[m][reg] = cmask[b * LC + i0 + il];
        }
    #pragma unroll
    for (int m = 0; m < 4; ++m)
        #pragma unroll
        for (int n = 0; n < 4; ++n)
            #pragma unroll
            for (int reg = 0; reg < 4; ++reg) {
                float v = acc[m][n][reg] + s0r[m][reg] + s1v[n];
                short sb = f2b(v);
                int il = wr * 64 + m * 16 + (l >> 4) * 4 + reg;
                int j = wc * 64 + n * 16 + (l & 15);
                Sb[((size_t)b * LC + i0 + il) * LQ + j] = sb;
                acc[m][n][reg] = b2f(sb);
            }

    // column-softmax partial stats (over the 128 i-rows in this block)
    #pragma unroll
    for (int n = 0; n < 4; ++n) {
        float x2v[16];
        float mx = NEGINF;
        #pragma unroll
        for (int m = 0; m < 4; ++m)
            #pragma unroll
            for (int reg = 0; reg < 4; ++reg) {
                float cm = cmr[m][reg];
                float x2 = acc[m][n][reg] * cm + (1.f - cm) * NEGINF;
                x2v[m * 4 + reg] = x2;
                mx = fmaxf(mx, x2);
            }
        float ss = 0.f;
        #pragma unroll
        for (int e = 0; e < 16; ++e) ss += __expf(x2v[e] - mx);
        #pragma unroll
        for (int off = 16; off <= 32; off <<= 1) {
            float om = __shfl_xor(mx, off, 64);
            float os = __shfl_xor(ss, off, 64);
            float nm = fmaxf(mx, om);
            ss = ss * __expf(mx - nm) + os * __expf(om - nm);
            mx = nm;
        }
        if (l < 16) {
            int j = wc * 64 + n * 16 + l;
            size_t idx = ((size_t)b * 32 + blockIdx.x * 2 + wr) * LQ + j;
            pm[idx] = mx;
            ps[idx] = ss;
        }
    }

    // row-softmax stats: reduce over n (in-thread), l&15 (shfl), wc (LDS)
    #pragma unroll
    for (int m = 0; m < 4; ++m)
        #pragma unroll
        for (int reg = 0; reg < 4; ++reg) {
            float mx = NEGINF;
            #pragma unroll
            for (int n = 0; n < 4; ++n)
                mx = fmaxf(mx, fmaf(acc[m][n][reg], qmv[n], negq[n]));
            #pragma unroll
            for (int o = 1; o <= 8; o <<= 1) mx = fmaxf(mx, __shfl_xor(mx, o, 64));
            float ss = 0.f;
            #pragma unroll
            for (int n = 0; n < 4; ++n)
                ss += __expf(fmaf(acc[m][n][reg], qmv[n], negq[n]) - mx);
            #pragma unroll
            for (int o = 1; o <= 8; o <<= 1) ss += __shfl_xor(ss, o, 64);
            if ((l & 15) == 0) {
                int row = wr * 64 + m * 16 + (l >> 4) * 4 + reg;
                rmLds[row * 4 + wc] = mx;
                rsLds[row * 4 + wc] = ss;
            }
        }
    __syncthreads();
    if (t < 128) {
        float m0 = rmLds[t * 4 + 0], m1 = rmLds[t * 4 + 1];
        float m2 = rmLds[t * 4 + 2], m3 = rmLds[t * 4 + 3];
        float mm = fmaxf(fmaxf(m0, m1), fmaxf(m2, m3));
        float ss = rsLds[t * 4 + 0] * __expf(m0 - mm)
                 + rsLds[t * 4 + 1] * __expf(m1 - mm)
                 + rsLds[t * 4 + 2] * __expf(m2 - mm)
                 + rsLds[t * 4 + 3] * __expf(m3 - mm);
        rowC[b * LC + i0 + t] = mm + logf(ss);
    }
}

// ---------- k3: split-K partials of A2CT[d,j] = sum_i c[i,d] * P2[i,j] ----------
#define K3S 72   // padded LDS row stride (shorts)
__global__ __launch_bounds__(256) void k3_A2C(
        const short* __restrict__ c16, const short* __restrict__ Sb,
        const float* __restrict__ cmask,
        const float* __restrict__ pm, const float* __restrict__ ps,
        float* __restrict__ p3) {
    __shared__ short As[128 * K3S];   // [d][i]
    __shared__ short Bs[128 * K3S];   // [j][i]
    __shared__ float colCs[128];
    int b  = blockIdx.z;
    int ks = blockIdx.y;
    int d0 = (blockIdx.x >> 1) * 128;
    int j0 = (blockIdx.x & 1) * 128;
    int t = threadIdx.x, l = t & 63, w = t >> 6;
    int wr = w >> 1, wc = w & 1;

    // fused colC = m + log(Z) for this block's 128 columns
    if (t < 128) {
        float m = NEGINF, s = 0.f;
        for (int ch = 0; ch < 32; ++ch) {
            float pmv = pm[((size_t)b * 32 + ch) * LQ + j0 + t];
            float psv = ps[((size_t)b * 32 + ch) * LQ + t + j0];
            float mn = fmaxf(m, pmv);
            s = s * __expf(m - mn) + psv * __expf(pmv - mn);
            m = mn;
        }
        colCs[t] = m + logf(s);
    }
    __syncthreads();

    f32x4 acc[4][4];
    #pragma unroll
    for (int m = 0; m < 4; ++m)
        #pragma unroll
        for (int n = 0; n < 4; ++n) acc[m][n] = (f32x4){0.f, 0.f, 0.f, 0.f};

    int ii = t >> 2;            // 0..63 : i within K-step
    int c4 = (t & 3) * 8;       // 16B sub-chunk

    for (int k0 = ks * 512; k0 < ks * 512 + 512; k0 += 64) {
        __syncthreads();
        float cm = cmask[b * LC + k0 + ii];
        float negc = (1.f - cm) * NEGINF;
        #pragma unroll
        for (int e = 0; e < 4; ++e) {
            int dpos = c4 + e * 32;   // 0..127
            bf16x8 av = *(const bf16x8*)(c16 +
                    ((size_t)(b * LC + k0 + ii)) * DD + d0 + dpos);
            #pragma unroll
            for (int g = 0; g < 8; ++g) As[(dpos + g) * K3S + ii] = av[g];

            int jpos = c4 + e * 32;
            bf16x8 sv8 = *(const bf16x8*)(Sb +
                    ((size_t)(b * LC + k0 + ii)) * LQ + j0 + jpos);
            #pragma unroll
            for (int g = 0; g < 8; ++g) {
                float p = __expf(fmaf(b2f(sv8[g]), cm, negc) - colCs[jpos + g]);
                Bs[(jpos + g) * K3S + ii] = f2b(p);
            }
        }
        __syncthreads();
        #pragma unroll
        for (int kf = 0; kf < 2; ++kf) {
            bf16x8 a[4], bb[4];
            #pragma unroll
            for (int m = 0; m < 4; ++m) {
                int row = wr * 64 + m * 16 + (l & 15);
                a[m] = *(const bf16x8*)((const char*)As +
                        row * (K3S * 2) + kf * 64 + (l >> 4) * 16);
            }
            #pragma unroll
            for (int n = 0; n < 4; ++n) {
                int row = wc * 64 + n * 16 + (l & 15);
                bb[n] = *(const bf16x8*)((const char*)Bs +
                        row * (K3S * 2) + kf * 64 + (l >> 4) * 16);
            }
            #pragma unroll
            for (int m = 0; m < 4; ++m)
                #pragma unroll
                for (int n = 0; n < 4; ++n)
                    acc[m][n] = MFMA16(a[m], bb[n], acc[m][n]);
        }
    }
    // write fp32 partial tile [128 d][128 j]
    float* P = p3 + (((size_t)b * 4 + ks) * 4 + blockIdx.x) * 16384;
    #pragma unroll
    for (int m = 0; m < 4; ++m)
        #pragma unroll
        for (int n = 0; n < 4; ++n)
            #pragma unroll
            for (int reg = 0; reg < 4; ++reg) {
                int ld = wr * 64 + m * 16 + (l >> 4) * 4 + reg;
                int lj = wc * 64 + n * 16 + (l & 15);
                P[ld * 128 + lj] = acc[m][n][reg];
            }
}

// ---------- k3r: reduce 4 K-split partials -> bf16 A2CT ----------
__global__ __launch_bounds__(256) void k3r_reduce(
        const float* __restrict__ p3, short* __restrict__ A2CT) {
    int b = blockIdx.y;
    int linear = blockIdx.x * 256 + threadIdx.x;   // 0..16383
    int d = linear >> 6;
    int j4 = (linear & 63) * 4;
    int tile = (d >> 7) * 2 + (j4 >> 7);
    int ld = d & 127, lj = j4 & 127;
    const float* base = p3 + (((size_t)b * 4) * 4 + tile) * 16384 + ld * 128 + lj;
    float4 s = {0.f, 0.f, 0.f, 0.f};
    #pragma unroll
    for (int ks = 0; ks < 4; ++ks) {
        float4 v = *(const float4*)(base + (size_t)ks * 4 * 16384);
        s.x += v.x; s.y += v.y; s.z += v.z; s.w += v.w;
    }
    short4 o;
    o.x = f2b(s.x); o.y = f2b(s.y); o.z = f2b(s.z); o.w = f2b(s.w);
    *(short4*)(A2CT + ((size_t)b * DD + d) * LQ + j4) = o;
}

// ---------- k4: LDS-free. P1 frags built in-reg from Sb+rowC; two GEMMs + epilogue
__global__ __launch_bounds__(256) void k4_out(
        const short* __restrict__ Sb, const short* __restrict__ qT16,
        const short* __restrict__ A2CT, const float* __restrict__ c,
        const float* __restrict__ qmask, const float* __restrict__ rowC,
        float* __restrict__ out) {
    int b = blockIdx.y, i0 = blockIdx.x * 64;
    int t = threadIdx.x, l = t & 63, w = t >> 6;
    int d0w = w * 64;

    float rC[4];
    #pragma unroll
    for (int m = 0; m < 4; ++m)
        rC[m] = rowC[b * LC + i0 + m * 16 + (l & 15)];

    f32x4 acc1[4][4], acc2[4][4];
    #pragma unroll
    for (int m = 0; m < 4; ++m)
        #pragma unroll
        for (int n = 0; n < 4; ++n) {
            acc1[m][n] = (f32x4){0.f, 0.f, 0.f, 0.f};
            acc2[m][n] = (f32x4){0.f, 0.f, 0.f, 0.f};
        }
    const short* Sr  = Sb   + ((size_t)b * LC + i0) * LQ;
    const short* qTb = qT16 + (size_t)b * DD * LQ;
    const short* aTb = A2CT + (size_t)b * DD * LQ;

    for (int kf = 0; kf < 8; ++kf) {
        int j8 = kf * 32 + (l >> 4) * 8;
        float4 qa = *(const float4*)(qmask + b * LQ + j8);
        float4 qb2 = *(const float4*)(qmask + b * LQ + j8 + 4);
        float qm8[8] = {qa.x, qa.y, qa.z, qa.w, qb2.x, qb2.y, qb2.z, qb2.w};
        bf16x8 a[4];
        #pragma unroll
        for (int m = 0; m < 4; ++m) {
            bf16x8 s8 = *(const bf16x8*)(Sr + (size_t)(m * 16 + (l & 15)) * LQ + j8);
            #pragma unroll
            for (int g = 0; g < 8; ++g) {
                float x = fmaf(b2f(s8[g]), qm8[g], (1.f - qm8[g]) * NEGINF) - rC[m];
                a[m][g] = f2b(__expf(x));
            }
        }
        #pragma unroll
        for (int n = 0; n < 4; ++n) {
            int d = d0w + n * 16 + (l & 15);
            size_t off = (size_t)d * LQ + j8;
            bf16x8 bq = *(const bf16x8*)(qTb + off);
            bf16x8 ba = *(const bf16x8*)(aTb + off);
            #pragma unroll
            for (int m = 0; m < 4; ++m) {
                acc1[m][n] = MFMA16(a[m], bq, acc1[m][n]);
                acc2[m][n] = MFMA16(a[m], ba, acc2[m][n]);
            }
        }
    }
    #pragma unroll
    for (int m = 0; m < 4; ++m)
        #pragma unroll
        for (int n = 0; n < 4; ++n)
            #pragma unroll
            for (int reg = 0; reg < 4; ++reg) {
                int i = i0 + m * 16 + (l >> 4) * 4 + reg;
                int d = d0w + n * 16 + (l & 15);
                float cv = c[((size_t)b * LC + i) * DD + d];
                size_t ob = ((size_t)b * LC + i) * (size_t)(4 * DD);
                float v1 = acc1[m][n][reg], v2 = acc2[m][n][reg];
                out[ob + d]           = cv;
                out[ob + 256 + d]     = v1;
                out[ob + 512 + d]     = cv * v1;
                out[ob + 768 + d]     = cv * v2;
            }
}

extern "C" void kernel_launch(void* const* d_in, const int* in_sizes, int n_in,
                              void* d_out, int out_size, void* d_ws, size_t ws_size,
                              hipStream_t stream) {
    const float* c     = (const float*)d_in[0];
    const float* q     = (const float*)d_in[1];
    const float* cmask = (const float*)d_in[2];
    const float* qmask = (const float*)d_in[3];
    const float* cqw   = (const float*)d_in[4];
    const float* c_w   = (const float*)d_in[5];
    const float* q_w   = (const float*)d_in[6];
    const float* bias  = (const float*)d_in[7];
    float* out = (float*)d_out;

    char* w = (char*)d_ws;
    short* Sb    = (short*)(w);                  // 16,777,216 B
    short* c16   = (short*)(w + 16777216);       // 16,777,216 B
    short* qw16  = (short*)(w + 33554432);       //  2,097,152 B
    short* qT16  = (short*)(w + 35651584);       //  2,097,152 B
    short* A2CT  = (short*)(w + 37748736);       //  2,097,152 B
    float* s0c   = (float*)(w + 39845888);       //    131,072 B
    float* s1q   = (float*)(w + 39976960);       //     16,384 B
    float* pm    = (float*)(w + 39993344);       //    524,288 B
    float* ps    = (float*)(w + 40517632);       //    524,288 B
    float* p3    = (float*)(w + 41041920);       // 16,777,216 B
    float* rowC  = (float*)(w + 57819136);       //    131,072 B (end 57,950,208)

    prep_c<<<dim3(NB * LC / 8), dim3(256), 0, stream>>>(c, c_w, c16, s0c);
    prep_q<<<dim3(LQ / 64, NB), dim3(256), 0, stream>>>(
        q, cqw, q_w, bias, qw16, qT16, s1q);
    k1_S<<<dim3(LC / 128, NB), dim3(512), 0, stream>>>(
        c16, qw16, cmask, qmask, s0c, s1q, Sb, pm, ps, rowC);
    k3_A2C<<<dim3(4, 4, NB), dim3(256), 0, stream>>>(
        c16, Sb, cmask, pm, ps, p3);
    k3r_reduce<<<dim3(64, NB), dim3(256), 0, stream>>>(p3, A2CT);
    k4_out<<<dim3(LC / 64, NB), dim3(256), 0, stream>>>(
        Sb, qT16, A2CT, c, qmask, rowC, out);
}